// Round 3
// baseline (13.674 us; speedup 1.0000x reference)
//
#include <hip/hip_runtime.h>
#include <math.h>

// GATLayer fused kernel v3, MI355X (gfx950).
//
// Math (verified passing in R0/R1):
//  - receivers == senders => spatial_embed == b_sp (W_sp dead)
//  - rel_rec/rel_send one-hot => A[n][m] = lrelu(s_n + s_m + c) n!=m, 0 diag
//  - s_n = (bn.wa) + x_n . (Wn @ wa), c = bsp.wa + b_att
//  - softmax max-free (scores bounded, exp safe in fp32); diag exp(0)=1
//  - out[n][d] = rse_n * lrelu( sum_m E[n][m] * ne[m][d] )
//
// v3 vs v2 (latency-bound fix, round 2):
//  - 480 blocks x 512 threads (8 waves): wave owns 4 rows -> matmul pole halved
//    (256 readlane + 256 fmac per wave), 16 waves/CU for latency hiding
//  - wave-local softmax: 4 exps/lane, 4-step shuffle combine, E in padded LDS

namespace {

constexpr int Bb = 8, Nn = 64, Tt = 30, Ff = 4, Dd = 64;

__device__ __forceinline__ float lane_bcast(float v, int l) {
    return __int_as_float(__builtin_amdgcn_readlane(__float_as_int(v), l));
}

__global__ __launch_bounds__(512) void gat_fused(
    const float* __restrict__ x,     // [B][N][T][F]
    const float* __restrict__ Wn,    // [F][D]
    const float* __restrict__ bn,    // [D]
    const float* __restrict__ bsp,   // [D]
    const float* __restrict__ watt,  // [D]
    const float* __restrict__ batt,  // [1]
    float* __restrict__ out)         // [B][T][N][D]
{
    __shared__ float xs[Nn][Ff];      // 1 KB   x[b, :, t, :]
    __shared__ float ne[Nn][Dd];      // 16 KB  nodes_embed
    __shared__ float E[32][Nn + 1];   // 8.1 KB exp(scores) for this block's 32 rows
    __shared__ float sh_s[Nn];        // node attention scalars
    __shared__ float sh_rse[32];      // 1/denominator for this block's rows

    const int tid  = threadIdx.x;
    const int lane = tid & 63;
    const int wave = tid >> 6;        // 0..7
    const int blk  = blockIdx.x;
    const int bt   = blk >> 1;
    const int half = blk & 1;
    const int b    = bt / Tt;
    const int t    = bt - b * Tt;

    // x tile: first 256 threads load 256 floats
    if (tid < 256) {
        const int n = tid >> 2, f = tid & 3;
        xs[n][f] = x[(((size_t)b * Nn + n) * Tt + t) * Ff + f];
    }

    // per-lane weight columns (lane = d)
    const float w0 = Wn[0 * Dd + lane], w1 = Wn[1 * Dd + lane],
                w2 = Wn[2 * Dd + lane], w3 = Wn[3 * Dd + lane];
    const float bnd = bn[lane];
    const float wa  = watt[lane];

    // one-time butterflies: r0..r3 = Wn@wa, r4 = bn.wa, r5 = bsp.wa
    float r0 = w0 * wa, r1 = w1 * wa, r2 = w2 * wa, r3 = w3 * wa,
          r4 = bnd * wa, r5 = bsp[lane] * wa;
    #pragma unroll
    for (int off = 32; off >= 1; off >>= 1) {
        r0 += __shfl_xor(r0, off, 64);
        r1 += __shfl_xor(r1, off, 64);
        r2 += __shfl_xor(r2, off, 64);
        r3 += __shfl_xor(r3, off, 64);
        r4 += __shfl_xor(r4, off, 64);
        r5 += __shfl_xor(r5, off, 64);
    }
    const float cadd = r5 + batt[0];

    __syncthreads();   // xs ready

    // node scores (wave 0)
    if (wave == 0) {
        const float4 xl = *reinterpret_cast<const float4*>(&xs[lane][0]);
        sh_s[lane] = r4 + xl.x * r0 + xl.y * r1 + xl.z * r2 + xl.w * r3;
    }

    // nodes_embed: wave computes 8 rows, lane = d
    #pragma unroll
    for (int k = 0; k < 8; ++k) {
        const int n = wave * 8 + k;
        const float4 xn = *reinterpret_cast<const float4*>(&xs[n][0]);
        ne[n][lane] = bnd + xn.x * w0 + xn.y * w1 + xn.z * w2 + xn.w * w3;
    }
    __syncthreads();   // ne, sh_s ready

    // my ne column: col[m] = ne[m][lane] (2-way banks = free)
    float col[64];
    #pragma unroll
    for (int m = 0; m < 64; ++m) col[m] = ne[m][lane];

    // wave-local softmax for this wave's 4 rows.
    // lane = mq*4 + rl: row-local rl in [0,4), m-quarter mq in [0,16) covers m=4mq..4mq+3
    {
        const int rl = lane & 3, mq = lane >> 2;
        const int lrow = wave * 4 + rl;            // block-local row in [0,32)
        const int r    = half * 32 + lrow;         // global row
        const float srow = sh_s[r];
        float se = 0.0f;
        #pragma unroll
        for (int i = 0; i < 4; ++i) {
            const int m = mq * 4 + i;
            const float v = srow + sh_s[m] + cadd;
            float e = __expf(fmaxf(v, 0.01f * v));   // exp(lrelu(v))
            e = (m == r) ? 1.0f : e;                 // diag: exp(0) = 1
            E[lrow][m] = e;
            se += e;
        }
        se += __shfl_xor(se, 4, 64);
        se += __shfl_xor(se, 8, 64);
        se += __shfl_xor(se, 16, 64);
        se += __shfl_xor(se, 32, 64);
        if (lane < 4) sh_rse[wave * 4 + lane] = __builtin_amdgcn_rcpf(se);
    }
    __syncthreads();   // E, sh_rse ready (cross-lane LDS visibility)

    // matmul: wave's rows n = half*32 + wave*4 + k, k<4; lane = d
    float pr[4], rs[4], acc[4];
    #pragma unroll
    for (int k = 0; k < 4; ++k) {
        pr[k]  = E[wave * 4 + k][lane];
        rs[k]  = sh_rse[wave * 4 + k];
        acc[k] = 0.0f;
    }
    #pragma unroll
    for (int m = 0; m < 64; ++m) {
        const float cm = col[m];
        #pragma unroll
        for (int k = 0; k < 4; ++k)
            acc[k] = fmaf(lane_bcast(pr[k], m), cm, acc[k]);
    }

    float* op = out + (((size_t)bt) * Nn + half * 32 + wave * 4) * Dd + lane;
    #pragma unroll
    for (int k = 0; k < 4; ++k) {
        const float z = acc[k];
        op[k * Dd] = rs[k] * fmaxf(z, 0.01f * z);
    }
}

} // namespace

extern "C" void kernel_launch(void* const* d_in, const int* in_sizes, int n_in,
                              void* d_out, int out_size, void* d_ws, size_t ws_size,
                              hipStream_t stream) {
    const float* x    = (const float*)d_in[0];
    // d_in[1] rel_rec, d_in[2] rel_send: one-hot, folded into indexing (unused)
    const float* Wn   = (const float*)d_in[3];
    const float* bn   = (const float*)d_in[4];
    // d_in[5] W_sp: dead (spatial_relations == 0)
    const float* bsp  = (const float*)d_in[6];
    const float* watt = (const float*)d_in[7];
    const float* batt = (const float*)d_in[8];
    float* out = (float*)d_out;

    gat_fused<<<dim3(Bb * Tt * 2), dim3(512), 0, stream>>>(x, Wn, bn, bsp, watt, batt, out);
}

// Round 4
// 11.088 us; speedup vs baseline: 1.2332x; 1.2332x over previous
//
#include <hip/hip_runtime.h>
#include <math.h>

// GATLayer fused kernel v4, MI355X (gfx950).
//
// Math (verified passing R0-R2):
//  - receivers == senders => spatial_embed == b_sp (W_sp dead)
//  - rel_rec/rel_send one-hot => A[n][m] = lrelu(s_n + s_m + c) n!=m, 0 diag
//  - s_n = (bn.wa) + x_n . (Wn @ wa), c = bsp.wa + b_att
//  - softmax max-free (scores bounded, fp32-safe); diag exp(0)=1
//  - out[n][d] = rse_n * lrelu( sum_m E[n][m] * ne[m][d] )
//
// v4 vs v2 (issue-throughput fix):
//  - matmul A-broadcast via wave-uniform ds_read_b128 of E rows (4 values/inst,
//    broadcast = conflict-free) instead of 512 v_readlane -> VALU work halved,
//    broadcast moved to the otherwise-idle LDS pipe
//  - softmax computed only for the block's own 32 rows (v2 did all 64: 2x waste)
//  - E rows padded to 68 floats (272B = 17x16B) for 16B-aligned uniform b128 reads

namespace {

constexpr int Bb = 8, Nn = 64, Tt = 30, Ff = 4, Dd = 64;

__global__ __launch_bounds__(256) void gat_fused(
    const float* __restrict__ x,     // [B][N][T][F]
    const float* __restrict__ Wn,    // [F][D]
    const float* __restrict__ bn,    // [D]
    const float* __restrict__ bsp,   // [D]
    const float* __restrict__ watt,  // [D]
    const float* __restrict__ batt,  // [1]
    float* __restrict__ out)         // [B][T][N][D]
{
    __shared__ float xs[Nn][Ff];               // 1 KB
    __shared__ float ne[Nn][Dd];               // 16 KB
    __shared__ __align__(16) float E[32][68];  // 8.5 KB, rows 16B-aligned
    __shared__ float sh_s[Nn];
    __shared__ float sh_rse[32];

    const int tid  = threadIdx.x;
    const int lane = tid & 63;
    const int wave = tid >> 6;        // 0..3
    const int blk  = blockIdx.x;
    const int bt   = blk >> 1;
    const int half = blk & 1;
    const int b    = bt / Tt;
    const int t    = bt - b * Tt;

    // x tile: thread -> (n = tid/4, f = tid%4)
    {
        const int n = tid >> 2, f = tid & 3;
        xs[n][f] = x[(((size_t)b * Nn + n) * Tt + t) * Ff + f];
    }

    // per-lane weight columns (lane = d)
    const float w0 = Wn[0 * Dd + lane], w1 = Wn[1 * Dd + lane],
                w2 = Wn[2 * Dd + lane], w3 = Wn[3 * Dd + lane];
    const float bnd = bn[lane];
    const float wa  = watt[lane];

    // one-time butterflies: r0..r3 = Wn@wa, r4 = bn.wa, r5 = bsp.wa
    float r0 = w0 * wa, r1 = w1 * wa, r2 = w2 * wa, r3 = w3 * wa,
          r4 = bnd * wa, r5 = bsp[lane] * wa;
    #pragma unroll
    for (int off = 32; off >= 1; off >>= 1) {
        r0 += __shfl_xor(r0, off, 64);
        r1 += __shfl_xor(r1, off, 64);
        r2 += __shfl_xor(r2, off, 64);
        r3 += __shfl_xor(r3, off, 64);
        r4 += __shfl_xor(r4, off, 64);
        r5 += __shfl_xor(r5, off, 64);
    }
    const float cadd = r5 + batt[0];

    __syncthreads();   // xs ready

    // node scores (wave 0)
    if (wave == 0) {
        const float4 xl = *reinterpret_cast<const float4*>(&xs[lane][0]);
        sh_s[lane] = r4 + xl.x * r0 + xl.y * r1 + xl.z * r2 + xl.w * r3;
    }

    // nodes_embed: wave computes 16 rows, lane = d
    #pragma unroll
    for (int k = 0; k < 16; ++k) {
        const int n = wave * 16 + k;
        const float4 xn = *reinterpret_cast<const float4*>(&xs[n][0]);
        ne[n][lane] = bnd + xn.x * w0 + xn.y * w1 + xn.z * w2 + xn.w * w3;
    }
    __syncthreads();   // ne, sh_s ready

    // my ne column: col[m] = ne[m][lane] (2-way banks = free)
    float col[64];
    #pragma unroll
    for (int m = 0; m < 64; ++m) col[m] = ne[m][lane];

    // softmax for this block's 32 rows only; wave owns 8 rows.
    // lane = (mq<<3)|rl: row-local rl in [0,8), m-octet mq in [0,8) covers m=8mq..8mq+7
    {
        const int rl = lane & 7, mq = lane >> 3;
        const int lrow = wave * 8 + rl;            // block-local row [0,32)
        const int r    = half * 32 + lrow;         // global row
        const float srow = sh_s[r];
        float se = 0.0f;
        #pragma unroll
        for (int i = 0; i < 8; ++i) {
            const int m = mq * 8 + i;
            const float v = srow + sh_s[m] + cadd;
            float e = __expf(fmaxf(v, 0.01f * v));   // exp(lrelu(v))
            e = (m == r) ? 1.0f : e;                 // diag: exp(0) = 1
            E[lrow][m] = e;
            se += e;
        }
        se += __shfl_xor(se, 8, 64);
        se += __shfl_xor(se, 16, 64);
        se += __shfl_xor(se, 32, 64);
        if (lane < 8) sh_rse[wave * 8 + lane] = __builtin_amdgcn_rcpf(se);
    }
    __syncthreads();   // E, sh_rse ready

    // matmul: wave's 8 rows; lane = d. A-broadcast via wave-uniform float4 LDS
    // reads; q-outer / k-inner gives 8 independent acc chains (issue-bound, ILP=8)
    float acc[8];
    #pragma unroll
    for (int k = 0; k < 8; ++k) acc[k] = 0.0f;
    #pragma unroll
    for (int q = 0; q < 16; ++q) {
        const float c0 = col[4 * q + 0], c1 = col[4 * q + 1],
                    c2 = col[4 * q + 2], c3 = col[4 * q + 3];
        #pragma unroll
        for (int k = 0; k < 8; ++k) {
            const float4 e4 = *reinterpret_cast<const float4*>(&E[wave * 8 + k][4 * q]);
            acc[k] = fmaf(e4.x, c0, acc[k]);
            acc[k] = fmaf(e4.y, c1, acc[k]);
            acc[k] = fmaf(e4.z, c2, acc[k]);
            acc[k] = fmaf(e4.w, c3, acc[k]);
        }
    }

    float* op = out + ((size_t)bt * Nn + half * 32 + wave * 8) * Dd + lane;
    #pragma unroll
    for (int k = 0; k < 8; ++k) {
        const float rs = sh_rse[wave * 8 + k];
        const float z  = acc[k];
        op[k * Dd] = rs * fmaxf(z, 0.01f * z);
    }
}

} // namespace

extern "C" void kernel_launch(void* const* d_in, const int* in_sizes, int n_in,
                              void* d_out, int out_size, void* d_ws, size_t ws_size,
                              hipStream_t stream) {
    const float* x    = (const float*)d_in[0];
    // d_in[1] rel_rec, d_in[2] rel_send: one-hot, folded into indexing (unused)
    const float* Wn   = (const float*)d_in[3];
    const float* bn   = (const float*)d_in[4];
    // d_in[5] W_sp: dead (spatial_relations == 0)
    const float* bsp  = (const float*)d_in[6];
    const float* watt = (const float*)d_in[7];
    const float* batt = (const float*)d_in[8];
    float* out = (float*)d_out;

    gat_fused<<<dim3(Bb * Tt * 2), dim3(256), 0, stream>>>(x, Wn, bn, bsp, watt, batt, out);
}